// Round 1
// baseline (640.056 us; speedup 1.0000x reference)
//
#include <hip/hip_runtime.h>
#include <hip/hip_bf16.h>

// out[65536,1800] = ReLU(A[65536,72] @ W[1800,72]^T + b)
// A = x viewed flat: chunk c = x[4c..4c+4)[6][3] = 72 contiguous floats.

typedef __bf16 bf16;
typedef bf16  bf16x4 __attribute__((ext_vector_type(4)));
typedef bf16  bf16x8 __attribute__((ext_vector_type(8)));
typedef float f32x4  __attribute__((ext_vector_type(4)));

#define KDIM 72
#define LDK  104   // LDS row stride in bf16: 208 B (16B-aligned, non-pow2 bank stride)
#define NDIM 1800
#define BM   64
#define BN   64

__global__ __launch_bounds__(256, 4)
void edges_mlp_kernel(const float* __restrict__ A,    // [M][72]
                      const float* __restrict__ W,    // [1800][72]
                      const float* __restrict__ bias, // [1800]
                      float* __restrict__ out)        // [M][1800]
{
    __shared__ bf16 As[BM][LDK];
    __shared__ bf16 Bs[BN][LDK];

    const int t  = threadIdx.x;
    const int n0 = blockIdx.x * BN;
    const int m0 = blockIdx.y * BM;

    // ---- zero-fill K pad region [72,96) for both tiles: 3 x 16B per row ----
    for (int idx = t; idx < BM * 3 * 2; idx += 256) {
        int half = idx / (BM * 3);
        int rem  = idx % (BM * 3);
        int r    = rem / 3;
        int part = rem % 3;
        char* base = half ? (char*)&Bs[r][0] : (char*)&As[r][0];
        *(uint4*)(base + KDIM * 2 + part * 16) = make_uint4(0u, 0u, 0u, 0u);
    }

    // ---- stage A tile: 64 rows x 72 fp32 = 1152 float4, cvt -> bf16 LDS ----
    const float4* A4 = (const float4*)(A + (size_t)m0 * KDIM);
    for (int i = t; i < BM * (KDIM / 4); i += 256) {
        int m = i / (KDIM / 4);
        int q = i % (KDIM / 4);
        float4 v = A4[i];
        bf16x4 h = { (bf16)v.x, (bf16)v.y, (bf16)v.z, (bf16)v.w };
        *(bf16x4*)&As[m][q * 4] = h;
    }
    // ---- stage B tile (W rows), bounds-checked (last N-tile is partial) ----
    for (int i = t; i < BN * (KDIM / 4); i += 256) {
        int n = i / (KDIM / 4);
        int q = i % (KDIM / 4);
        int gn = n0 + n;
        float4 v = make_float4(0.f, 0.f, 0.f, 0.f);
        if (gn < NDIM) v = *(const float4*)(W + (size_t)gn * KDIM + q * 4);
        bf16x4 h = { (bf16)v.x, (bf16)v.y, (bf16)v.z, (bf16)v.w };
        *(bf16x4*)&Bs[n][q * 4] = h;
    }
    __syncthreads();

    const int wave = t >> 6;
    const int lane = t & 63;
    const int lrow = lane & 15;        // fragment row (A) / col (B) selector
    const int lkb  = (lane >> 4) * 8;  // k offset within 32-wide k-step

    f32x4 acc[4] = { {0,0,0,0}, {0,0,0,0}, {0,0,0,0}, {0,0,0,0} };

    #pragma unroll
    for (int ks = 0; ks < 3; ++ks) {
        bf16x8 a = *(const bf16x8*)&As[wave * 16 + lrow][ks * 32 + lkb];
        #pragma unroll
        for (int nt = 0; nt < 4; ++nt) {
            bf16x8 bf = *(const bf16x8*)&Bs[nt * 16 + lrow][ks * 32 + lkb];
            acc[nt] = __builtin_amdgcn_mfma_f32_16x16x32_bf16(a, bf, acc[nt], 0, 0, 0);
        }
    }

    // ---- epilogue: bias + ReLU + store ----
    // D layout (m89-verified): lane l, reg r -> row=(l>>4)*4+r, col=l&15
    const int orow0 = m0 + wave * 16 + (lane >> 4) * 4;
    #pragma unroll
    for (int nt = 0; nt < 4; ++nt) {
        int col = n0 + nt * 16 + lrow;
        if (col < NDIM) {
            float bv = bias[col];
            #pragma unroll
            for (int r = 0; r < 4; ++r) {
                float v = fmaxf(acc[nt][r] + bv, 0.0f);
                __builtin_nontemporal_store(v, &out[(size_t)(orow0 + r) * NDIM + col]);
            }
        }
    }
}

extern "C" void kernel_launch(void* const* d_in, const int* in_sizes, int n_in,
                              void* d_out, int out_size, void* d_ws, size_t ws_size,
                              hipStream_t stream) {
    const float* x = (const float*)d_in[0];
    const float* W = (const float*)d_in[1];
    const float* b = (const float*)d_in[2];
    float* out = (float*)d_out;

    const int chunks = in_sizes[0] / KDIM;          // 65536
    dim3 grid((NDIM + BN - 1) / BN, chunks / BM);   // (29, 1024), x fastest: share A panel
    edges_mlp_kernel<<<grid, 256, 0, stream>>>(x, W, b, out);
}